// Round 4
// baseline (260.284 us; speedup 1.0000x reference)
//
#include <hip/hip_runtime.h>
#include <cstdint>

#define B_   16
#define H_   128
#define W_   128
#define C_   64
#define HID_ 256
#define XELEMS (B_ * H_ * W_ * C_)   // 16777216

typedef __attribute__((ext_vector_type(8))) short short8v;   // 8 bf16
typedef __attribute__((ext_vector_type(4))) float f32x4;
typedef unsigned short ushort_t;

// ws layout (elements of ushort_t)
#define W1S_OFF 0
#define W2S_OFF 81920
#define CWB_OFF 98304
#define XBF_OFF 100608
#define WS_NEED_BYTES (2u * XBF_OFF + 2u * XELEMS)

__device__ __forceinline__ ushort_t f2bf(float f) {
  uint32_t u = __builtin_bit_cast(uint32_t, f);
  u += 0x7fff + ((u >> 16) & 1);          // round-to-nearest-even
  return (ushort_t)(u >> 16);
}
__device__ __forceinline__ float bf_lo(uint32_t u) {   // low bf16 -> f32
  return __builtin_bit_cast(float, u << 16);
}
__device__ __forceinline__ float bf_hi(uint32_t u) {   // high bf16 -> f32
  return __builtin_bit_cast(float, u & 0xffff0000u);
}

// XOR-swizzled LDS index, row stride 256 ushorts (512 B == 0 mod 32 banks).
// BIJECTIVE swizzle: XOR the 3-bit (row&7) into the FULL-width 5-bit granule
// index (only flips its low 3 bits; bits 3-4 survive). Round-3 bug: masking
// the whole granule index to 3 bits collapsed 32 granules onto 8 -> LDS
// write collisions -> absmax 5.25. 16 rows per ds_read_b128 -> 2-way (free).
__device__ __forceinline__ int hs(int row, int col) {
  return row * 256 + (((col >> 3) ^ (row & 7)) << 3) + (col & 7);
}

// fast tanh-GELU: gelu(h) = h * sigmoid(h*(c0 + c1*h^2)) in exp2 domain
// (matches 0.7978845608*(h + 0.044715 h^3) after the ln2 fold)
__device__ __forceinline__ float fast_gelu(float h) {
  float u = h * fmaf(h * h, 0.10293921f, 2.30211813f);
  float e = exp2f(-u);
  return h * __builtin_amdgcn_rcpf(1.0f + e);
}

// ---------------------------------------------------------------------------
// cvt_x: x fp32 -> bf16 copy in ws (8 elems/thread, exact grid)
// ---------------------------------------------------------------------------
__global__ void cvt_x_kernel(const float* __restrict__ x,
                             ushort_t* __restrict__ xb) {
  int i = (blockIdx.x * 256 + threadIdx.x) * 8;
  const float4 a = *(const float4*)&x[i];
  const float4 b = *(const float4*)&x[i + 4];
  short8v o;
  o[0] = (short)f2bf(a.x); o[1] = (short)f2bf(a.y);
  o[2] = (short)f2bf(a.z); o[3] = (short)f2bf(a.w);
  o[4] = (short)f2bf(b.x); o[5] = (short)f2bf(b.y);
  o[6] = (short)f2bf(b.z); o[7] = (short)f2bf(b.w);
  *(short8v*)&xb[i] = o;
}

// ---------------------------------------------------------------------------
// cvt_weights: W1/W2 -> bf16 MFMA B-fragments, conv_w -> bf16 flat
//   B-frag: lane l needs B[k0 + (l>>4)*8 + j][n0 + (l&15)], j=0..7, 16B/lane
// ---------------------------------------------------------------------------
__global__ void cvt_weights_kernel(const float* __restrict__ W1,
                                   const float* __restrict__ W2,
                                   const float* __restrict__ cw,
                                   ushort_t* __restrict__ w1s,
                                   ushort_t* __restrict__ w2s,
                                   ushort_t* __restrict__ cwb) {
  int t = blockIdx.x * 256 + threadIdx.x;
  if (t < 81920) {
    int j = t & 7, lane = (t >> 3) & 63, n16 = (t >> 9) & 15, ks = t >> 13;
    int k = ks * 32 + (lane >> 4) * 8 + j;
    int n = n16 * 16 + (lane & 15);
    w1s[t] = f2bf(W1[k * 256 + n]);
  } else if (t < 98304) {
    int t2 = t - 81920;
    int j = t2 & 7, lane = (t2 >> 3) & 63, n16 = (t2 >> 9) & 3, ks = t2 >> 11;
    int k = ks * 32 + (lane >> 4) * 8 + j;
    int n = n16 * 16 + (lane & 15);
    w2s[t2] = f2bf(W2[k * 64 + n]);
  } else if (t < 98304 + 2304) {
    int t3 = t - 98304;
    cwb[t3] = f2bf(cw[t3]);       // [(dd*9 + ky*3+kx)*64 + ch]
  }
}

// ---------------------------------------------------------------------------
// Depthwise dilated conv phase. BF16X: taps from bf16 x copy (8B loads +
// shift-unpack); else fp32 x (fallback when ws too small).
// ---------------------------------------------------------------------------
template <bool BOUND, bool BF16X>
__device__ __forceinline__ void conv_phase(const float* __restrict__ xb,
                                           const ushort_t* __restrict__ xbb,
                                           const ushort_t* __restrict__ cwb,
                                           ushort_t* __restrict__ feat,
                                           int tid, int tileX, int tileY) {
  const int quad = tid & 15;
  const int p0   = tid >> 4;
#pragma unroll
  for (int dd = 0; dd < 4; ++dd) {
    const int dil = 1 << dd;
    float wv[9][4];
#pragma unroll
    for (int t = 0; t < 9; ++t) {
      uint2 w2 = *(const uint2*)&cwb[(dd * 9 + t) * C_ + quad * 4];
      wv[t][0] = bf_lo(w2.x); wv[t][1] = bf_hi(w2.x);
      wv[t][2] = bf_lo(w2.y); wv[t][3] = bf_hi(w2.y);
    }
#pragma unroll
    for (int i = 0; i < 4; ++i) {
      const int p  = i * 16 + p0;
      const int py = p >> 3, px = p & 7;
      const int y0 = tileY + py, x0 = tileX + px;
      float a0 = 0.f, a1 = 0.f, a2 = 0.f, a3 = 0.f;
#pragma unroll
      for (int ky = 0; ky < 3; ++ky) {
        const int yy = y0 + (ky - 1) * dil;
        if (BOUND && (unsigned)yy >= (unsigned)H_) continue;
#pragma unroll
        for (int kx = 0; kx < 3; ++kx) {
          const int xx = x0 + (kx - 1) * dil;
          if (BOUND && (unsigned)xx >= (unsigned)W_) continue;
          if (BF16X) {
            uint2 v = *(const uint2*)&xbb[(yy * W_ + xx) * C_ + quad * 4];
            a0 = fmaf(bf_lo(v.x), wv[ky * 3 + kx][0], a0);
            a1 = fmaf(bf_hi(v.x), wv[ky * 3 + kx][1], a1);
            a2 = fmaf(bf_lo(v.y), wv[ky * 3 + kx][2], a2);
            a3 = fmaf(bf_hi(v.y), wv[ky * 3 + kx][3], a3);
          } else {
            const float4 xv = *(const float4*)&xb[(yy * W_ + xx) * C_ + quad * 4];
            a0 = fmaf(xv.x, wv[ky * 3 + kx][0], a0);
            a1 = fmaf(xv.y, wv[ky * 3 + kx][1], a1);
            a2 = fmaf(xv.z, wv[ky * 3 + kx][2], a2);
            a3 = fmaf(xv.w, wv[ky * 3 + kx][3], a3);
          }
        }
      }
      ushort4 pk;
      pk.x = f2bf(a0); pk.y = f2bf(a1); pk.z = f2bf(a2); pk.w = f2bf(a3);
      *(ushort4*)&feat[hs(p, dd * 64 + quad * 4)] = pk;
    }
  }
}

// ---------------------------------------------------------------------------
// Fused NCA kernel: one block = 8x8 pixel tile, 256 threads, 32 KB LDS.
// feat[64][256] holds conv outputs only (K-channels 64..319); GEMM1's
// K in [0,64) A-fragments come straight from global bf16 x (already in
// fragment order). hbuf aliases feat exactly.
// ---------------------------------------------------------------------------
template <bool BF16X>
__global__ __launch_bounds__(256, 4)
void nca_fused_kernel(const float* __restrict__ x,
                      const ushort_t* __restrict__ xbf,
                      const ushort_t* __restrict__ cwb,
                      const float* __restrict__ b1,
                      const float* __restrict__ b2,
                      const ushort_t* __restrict__ w1s,
                      const ushort_t* __restrict__ w2s,
                      float* __restrict__ out) {
  __shared__ __align__(16) ushort_t smem[64 * 256];   // 32768 B

  const int tid   = threadIdx.x;
  const int tileX = blockIdx.x * 8;
  const int tileY = blockIdx.y * 8;
  const int batch = blockIdx.z;
  const float*    xb  = x   + (size_t)batch * (H_ * W_ * C_);
  const ushort_t* xbb = xbf + (size_t)batch * (H_ * W_ * C_);

  const int lane = tid & 63;
  const int wv   = tid >> 6;
  const int lr   = lane & 15;
  const int lg   = lane >> 4;
  const int n0   = wv * 64;

  // ---- issue GEMM1 ks=0,1 A-fragments (x channels 0..63) early: global,
  //      latency hidden under the whole conv phase ----
  short8v xf[4][2];
#pragma unroll
  for (int mi = 0; mi < 4; ++mi) {
    const int p = mi * 16 + lr;
    const int gp = (tileY + (p >> 3)) * W_ + tileX + (p & 7);
    if (BF16X) {
#pragma unroll
      for (int ks = 0; ks < 2; ++ks)
        xf[mi][ks] = *(const short8v*)&xbb[gp * C_ + ks * 32 + lg * 8];
    } else {
#pragma unroll
      for (int ks = 0; ks < 2; ++ks) {
        const float* bp = &xb[gp * C_ + ks * 32 + lg * 8];
        float4 u = *(const float4*)bp, v = *(const float4*)(bp + 4);
        short8v s;
        s[0] = (short)f2bf(u.x); s[1] = (short)f2bf(u.y);
        s[2] = (short)f2bf(u.z); s[3] = (short)f2bf(u.w);
        s[4] = (short)f2bf(v.x); s[5] = (short)f2bf(v.y);
        s[6] = (short)f2bf(v.z); s[7] = (short)f2bf(v.w);
        xf[mi][ks] = s;
      }
    }
  }

  // ---- conv phase ----
  const bool interior = (tileX >= 8) && (tileX <= W_ - 16) &&
                        (tileY >= 8) && (tileY <= H_ - 16);
  if (interior)
    conv_phase<false, BF16X>(xb, xbb, cwb, smem, tid, tileX, tileY);
  else
    conv_phase<true, BF16X>(xb, xbb, cwb, smem, tid, tileX, tileY);
  __syncthreads();

  // ---- GEMM1: [64 x 320] @ [320 x 256] ----
  f32x4 acc[4][4];
#pragma unroll
  for (int mi = 0; mi < 4; ++mi)
#pragma unroll
    for (int ni = 0; ni < 4; ++ni) acc[mi][ni] = 0;

  const short8v* w1v = (const short8v*)w1s;
#pragma unroll
  for (int ks = 0; ks < 2; ++ks) {       // K 0..63 from registers
    short8v bf[4];
#pragma unroll
    for (int ni = 0; ni < 4; ++ni)
      bf[ni] = w1v[(ks * 16 + wv * 4 + ni) * 64 + lane];
#pragma unroll
    for (int mi = 0; mi < 4; ++mi)
#pragma unroll
      for (int ni = 0; ni < 4; ++ni)
        acc[mi][ni] = __builtin_amdgcn_mfma_f32_16x16x32_bf16(
            xf[mi][ks], bf[ni], acc[mi][ni], 0, 0, 0);
  }
  for (int ks = 2; ks < 10; ++ks) {      // K 64..319 from LDS (conv out)
    short8v af[4], bf[4];
#pragma unroll
    for (int mi = 0; mi < 4; ++mi)
      af[mi] = *(const short8v*)&smem[hs(mi * 16 + lr, (ks - 2) * 32 + lg * 8)];
#pragma unroll
    for (int ni = 0; ni < 4; ++ni)
      bf[ni] = w1v[(ks * 16 + wv * 4 + ni) * 64 + lane];
#pragma unroll
    for (int mi = 0; mi < 4; ++mi)
#pragma unroll
      for (int ni = 0; ni < 4; ++ni)
        acc[mi][ni] = __builtin_amdgcn_mfma_f32_16x16x32_bf16(
            af[mi], bf[ni], acc[mi][ni], 0, 0, 0);
  }

  float bias1[4];
#pragma unroll
  for (int ni = 0; ni < 4; ++ni) bias1[ni] = b1[n0 + ni * 16 + lr];

  __syncthreads();   // all feat reads done; safe to alias with hbuf

  // ---- bias + fast GELU -> hbuf (aliases smem) ----
#pragma unroll
  for (int mi = 0; mi < 4; ++mi) {
#pragma unroll
    for (int ni = 0; ni < 4; ++ni) {
      const int col = n0 + ni * 16 + lr;
#pragma unroll
      for (int q = 0; q < 4; ++q) {
        float g = fast_gelu(acc[mi][ni][q] + bias1[ni]);
        smem[hs(mi * 16 + lg * 4 + q, col)] = f2bf(g);
      }
    }
  }
  __syncthreads();

  // ---- GEMM2: [64 x 256] @ [256 x 64]; wave w does rows 16w..16w+15 ----
  const int m0 = wv * 16;
  f32x4 acc2[4];
#pragma unroll
  for (int ni = 0; ni < 4; ++ni) acc2[ni] = 0;

  const short8v* w2v = (const short8v*)w2s;
  for (int ks = 0; ks < 8; ++ks) {
    short8v a2 = *(const short8v*)&smem[hs(m0 + lr, ks * 32 + lg * 8)];
#pragma unroll
    for (int ni = 0; ni < 4; ++ni) {
      short8v bfr = w2v[(ks * 4 + ni) * 64 + lane];
      acc2[ni] = __builtin_amdgcn_mfma_f32_16x16x32_bf16(a2, bfr, acc2[ni],
                                                         0, 0, 0);
    }
  }

  // ---- epilogue: out = x + delta + b2 (fp32 residual) ----
#pragma unroll
  for (int ni = 0; ni < 4; ++ni) {
    const int col  = ni * 16 + lr;
    const float bias = b2[col];
#pragma unroll
    for (int q = 0; q < 4; ++q) {
      const int row = m0 + lg * 4 + q;
      const int py = row >> 3, px = row & 7;
      const size_t idx =
          ((size_t)(batch * H_ + tileY + py) * W_ + (tileX + px)) * C_ + col;
      out[idx] = x[idx] + acc2[ni][q] + bias;
    }
  }
}

extern "C" void kernel_launch(void* const* d_in, const int* in_sizes, int n_in,
                              void* d_out, int out_size, void* d_ws,
                              size_t ws_size, hipStream_t stream) {
  const float* x  = (const float*)d_in[0];
  const float* cw = (const float*)d_in[1];
  const float* W1 = (const float*)d_in[2];
  const float* b1 = (const float*)d_in[3];
  const float* W2 = (const float*)d_in[4];
  const float* b2 = (const float*)d_in[5];
  float* out = (float*)d_out;

  ushort_t* wsb = (ushort_t*)d_ws;
  ushort_t* w1s = wsb + W1S_OFF;
  ushort_t* w2s = wsb + W2S_OFF;
  ushort_t* cwb = wsb + CWB_OFF;
  ushort_t* xbf = wsb + XBF_OFF;

  cvt_weights_kernel<<<393, 256, 0, stream>>>(W1, W2, cw, w1s, w2s, cwb);

  const bool bf16x = ws_size >= (size_t)WS_NEED_BYTES;
  dim3 grid(W_ / 8, H_ / 8, B_);              // 4096 blocks
  if (bf16x) {
    cvt_x_kernel<<<XELEMS / 8 / 256, 256, 0, stream>>>(x, xbf);
    nca_fused_kernel<true><<<grid, 256, 0, stream>>>(x, xbf, cwb, b1, b2,
                                                     w1s, w2s, out);
  } else {
    nca_fused_kernel<false><<<grid, 256, 0, stream>>>(x, xbf, cwb, b1, b2,
                                                      w1s, w2s, out);
  }
}

// Round 5
// 220.911 us; speedup vs baseline: 1.1782x; 1.1782x over previous
//
#include <hip/hip_runtime.h>
#include <cstdint>

#define B_   16
#define H_   128
#define W_   128
#define C_   64
#define HID_ 256
#define XELEMS (B_ * H_ * W_ * C_)   // 16777216

typedef _Float16 __attribute__((ext_vector_type(2))) half2v;
typedef _Float16 __attribute__((ext_vector_type(8))) half8v;   // 4 VGPRs, MFMA frag
typedef __attribute__((ext_vector_type(4))) float f32x4;
typedef unsigned short ushort_t;

// ws layout (elements of _Float16 / ushort)
#define W1S_OFF 0
#define W2S_OFF 81920
#define CWH_OFF 98304
#define XH_OFF  100608
#define WS_NEED_BYTES (2u * XH_OFF + 2u * XELEMS)

// XOR-swizzled LDS index, row stride 256 elems (512 B == 0 mod 32 banks).
// Bijective: XOR 3-bit (row&7) into the full 5-bit 16B-granule index.
__device__ __forceinline__ int hs(int row, int col) {
  return row * 256 + (((col >> 3) ^ (row & 7)) << 3) + (col & 7);
}

// fast tanh-GELU in exp2 domain
__device__ __forceinline__ float fast_gelu(float h) {
  float u = h * fmaf(h * h, 0.10293921f, 2.30211813f);
  float e = exp2f(-u);
  return h * __builtin_amdgcn_rcpf(1.0f + e);
}

// ---------------------------------------------------------------------------
// cvt_x: x fp32 -> fp16 copy in ws
// ---------------------------------------------------------------------------
__global__ void cvt_x_kernel(const float* __restrict__ x,
                             _Float16* __restrict__ xh) {
  int i = (blockIdx.x * 256 + threadIdx.x) * 8;
  const float4 a = *(const float4*)&x[i];
  const float4 b = *(const float4*)&x[i + 4];
  half8v o = {(_Float16)a.x, (_Float16)a.y, (_Float16)a.z, (_Float16)a.w,
              (_Float16)b.x, (_Float16)b.y, (_Float16)b.z, (_Float16)b.w};
  *(half8v*)&xh[i] = o;
}

// ---------------------------------------------------------------------------
// cvt_weights: W1/W2 -> fp16 MFMA fragments (lane l, j=0..7 holds
// M[k0+(l>>4)*8+j][n0+(l&15)], 16B/lane contiguous), conv_w -> fp16 flat.
// ---------------------------------------------------------------------------
__global__ void cvt_weights_kernel(const float* __restrict__ W1,
                                   const float* __restrict__ W2,
                                   const float* __restrict__ cw,
                                   _Float16* __restrict__ w1s,
                                   _Float16* __restrict__ w2s,
                                   _Float16* __restrict__ cwh) {
  int t = blockIdx.x * 256 + threadIdx.x;
  if (t < 81920) {
    int j = t & 7, lane = (t >> 3) & 63, n16 = (t >> 9) & 15, ks = t >> 13;
    int k = ks * 32 + (lane >> 4) * 8 + j;
    int n = n16 * 16 + (lane & 15);
    w1s[t] = (_Float16)W1[k * 256 + n];
  } else if (t < 98304) {
    int t2 = t - 81920;
    int j = t2 & 7, lane = (t2 >> 3) & 63, n16 = (t2 >> 9) & 3, ks = t2 >> 11;
    int k = ks * 32 + (lane >> 4) * 8 + j;
    int n = n16 * 16 + (lane & 15);
    w2s[t2] = (_Float16)W2[k * 64 + n];
  } else if (t < 98304 + 2304) {
    int t3 = t - 98304;
    cwh[t3] = (_Float16)cw[t3];   // [(dd*9 + ky*3+kx)*64 + ch]
  }
}

// ---------------------------------------------------------------------------
// Depthwise dilated conv phase, fp16 packed math (v_pk_fma_f16):
// per tap per 4ch: 1×8B load + 2 pk_fma, no unpack. FP16X=false falls back
// to fp32 x (ws too small).
// ---------------------------------------------------------------------------
template <bool BOUND, bool FP16X>
__device__ __forceinline__ void conv_phase(const float* __restrict__ xb,
                                           const _Float16* __restrict__ xhb,
                                           const _Float16* __restrict__ cwh,
                                           ushort_t* __restrict__ feat,
                                           int tid, int tileX, int tileY) {
  const int quad = tid & 15;
  const int p0   = tid >> 4;
#pragma unroll
  for (int dd = 0; dd < 4; ++dd) {
    const int dil = 1 << dd;
    half2v w01[9], w23[9];
#pragma unroll
    for (int t = 0; t < 9; ++t) {
      uint2 wr = *(const uint2*)&cwh[(dd * 9 + t) * C_ + quad * 4];
      w01[t] = __builtin_bit_cast(half2v, wr.x);
      w23[t] = __builtin_bit_cast(half2v, wr.y);
    }
#pragma unroll
    for (int i = 0; i < 4; ++i) {
      const int p  = i * 16 + p0;
      const int py = p >> 3, px = p & 7;
      const int y0 = tileY + py, x0 = tileX + px;
      half2v a01 = {0, 0}, a23 = {0, 0};
#pragma unroll
      for (int ky = 0; ky < 3; ++ky) {
        const int yy = y0 + (ky - 1) * dil;
        if (BOUND && (unsigned)yy >= (unsigned)H_) continue;
#pragma unroll
        for (int kx = 0; kx < 3; ++kx) {
          const int xx = x0 + (kx - 1) * dil;
          if (BOUND && (unsigned)xx >= (unsigned)W_) continue;
          const int t = ky * 3 + kx;
          if (FP16X) {
            uint2 v = *(const uint2*)&xhb[(yy * W_ + xx) * C_ + quad * 4];
            a01 += __builtin_bit_cast(half2v, v.x) * w01[t];
            a23 += __builtin_bit_cast(half2v, v.y) * w23[t];
          } else {
            const float4 xv = *(const float4*)&xb[(yy * W_ + xx) * C_ + quad * 4];
            half2v xl = {(_Float16)xv.x, (_Float16)xv.y};
            half2v xh2 = {(_Float16)xv.z, (_Float16)xv.w};
            a01 += xl * w01[t];
            a23 += xh2 * w23[t];
          }
        }
      }
      uint2 pk;
      pk.x = __builtin_bit_cast(uint32_t, a01);
      pk.y = __builtin_bit_cast(uint32_t, a23);
      *(uint2*)&feat[hs(p, dd * 64 + quad * 4)] = pk;
    }
  }
}

// ---------------------------------------------------------------------------
// Fused NCA kernel: one block = 8x8 pixel tile, 256 threads, 32 KB LDS.
// feat[64px][256ch] fp16 (conv outputs; x-channels K=0..63 of GEMM1 come
// straight from global fp16 x as B-fragments). GEMM1 computed SWAPPED:
// D[hid][pixel] = mfma(W1_frag, feat_frag) -> each lane's 4 regs are 4
// consecutive hid channels of ONE pixel -> GELU packs 8B LDS writes.
// hbuf[pixel][hid] aliases feat. GEMM2 unswapped: D[pixel][outch].
// ---------------------------------------------------------------------------
template <bool FP16X>
__global__ __launch_bounds__(256, 4)
void nca_fused_kernel(const float* __restrict__ x,
                      const _Float16* __restrict__ xh,
                      const _Float16* __restrict__ cwh,
                      const float* __restrict__ b1,
                      const float* __restrict__ b2,
                      const _Float16* __restrict__ w1s,
                      const _Float16* __restrict__ w2s,
                      float* __restrict__ out) {
  __shared__ __align__(16) ushort_t smem[64 * 256];   // 32768 B

  const int tid   = threadIdx.x;
  const int tileX = blockIdx.x * 8;
  const int tileY = blockIdx.y * 8;
  const int batch = blockIdx.z;
  const float*    xb  = x  + (size_t)batch * (H_ * W_ * C_);
  const _Float16* xhb = xh + (size_t)batch * (H_ * W_ * C_);

  const int lane = tid & 63;
  const int wv   = tid >> 6;
  const int lr   = lane & 15;
  const int lg   = lane >> 4;
  const int n0   = wv * 64;        // this wave's hid-block (GEMM1 M dim)

  // ---- GEMM1 k=0..63 B-fragments (x channels) issued early: latency
  //      hidden under the conv phase ----
  half8v xf[4][2];
#pragma unroll
  for (int pi = 0; pi < 4; ++pi) {
    const int p  = pi * 16 + lr;
    const int gp = (tileY + (p >> 3)) * W_ + tileX + (p & 7);
    if (FP16X) {
#pragma unroll
      for (int ks = 0; ks < 2; ++ks)
        xf[pi][ks] = *(const half8v*)&xhb[gp * C_ + ks * 32 + lg * 8];
    } else {
#pragma unroll
      for (int ks = 0; ks < 2; ++ks) {
        const float* bp = &xb[gp * C_ + ks * 32 + lg * 8];
        float4 u = *(const float4*)bp, v = *(const float4*)(bp + 4);
        half8v s = {(_Float16)u.x, (_Float16)u.y, (_Float16)u.z, (_Float16)u.w,
                    (_Float16)v.x, (_Float16)v.y, (_Float16)v.z, (_Float16)v.w};
        xf[pi][ks] = s;
      }
    }
  }

  // ---- conv phase ----
  const bool interior = (tileX >= 8) && (tileX <= W_ - 16) &&
                        (tileY >= 8) && (tileY <= H_ - 16);
  if (interior)
    conv_phase<false, FP16X>(xb, xhb, cwh, smem, tid, tileX, tileY);
  else
    conv_phase<true, FP16X>(xb, xhb, cwh, smem, tid, tileX, tileY);
  __syncthreads();

  // ---- GEMM1 (swapped): D[hid 256][px 64], wave owns hid-block n0..n0+63 ----
  f32x4 acc[4][4];   // [hi][pi]
#pragma unroll
  for (int hi = 0; hi < 4; ++hi)
#pragma unroll
    for (int pi = 0; pi < 4; ++pi) acc[hi][pi] = 0;

  const half8v* w1v = (const half8v*)w1s;
#pragma unroll
  for (int ks = 0; ks < 2; ++ks) {       // K 0..63 from registers
    half8v wf[4];
#pragma unroll
    for (int hi = 0; hi < 4; ++hi)
      wf[hi] = w1v[(ks * 16 + wv * 4 + hi) * 64 + lane];
#pragma unroll
    for (int hi = 0; hi < 4; ++hi)
#pragma unroll
      for (int pi = 0; pi < 4; ++pi)
        acc[hi][pi] = __builtin_amdgcn_mfma_f32_16x16x32_f16(
            wf[hi], xf[pi][ks], acc[hi][pi], 0, 0, 0);
  }
  for (int ks = 2; ks < 10; ++ks) {      // K 64..319 from LDS (conv out)
    half8v ff[4], wf[4];
#pragma unroll
    for (int pi = 0; pi < 4; ++pi)
      ff[pi] = *(const half8v*)&smem[hs(pi * 16 + lr, (ks - 2) * 32 + lg * 8)];
#pragma unroll
    for (int hi = 0; hi < 4; ++hi)
      wf[hi] = w1v[(ks * 16 + wv * 4 + hi) * 64 + lane];
#pragma unroll
    for (int hi = 0; hi < 4; ++hi)
#pragma unroll
      for (int pi = 0; pi < 4; ++pi)
        acc[hi][pi] = __builtin_amdgcn_mfma_f32_16x16x32_f16(
            wf[hi], ff[pi], acc[hi][pi], 0, 0, 0);
  }

  // per-lane bias: 4 consecutive hid channels per hi (float4)
  float4 bias1[4];
#pragma unroll
  for (int hi = 0; hi < 4; ++hi)
    bias1[hi] = *(const float4*)&b1[n0 + hi * 16 + lg * 4];

  __syncthreads();   // all feat reads done; safe to alias with hbuf

  // ---- bias + fast GELU -> hbuf[pixel][hid] (aliases smem), packed 8B ----
#pragma unroll
  for (int hi = 0; hi < 4; ++hi) {
#pragma unroll
    for (int pi = 0; pi < 4; ++pi) {
      _Float16 g[4];
#pragma unroll
      for (int q = 0; q < 4; ++q)
        g[q] = (_Float16)fast_gelu(acc[hi][pi][q] + bias1[hi][q]);
      half2v g01 = {g[0], g[1]}, g23 = {g[2], g[3]};
      uint2 pk;
      pk.x = __builtin_bit_cast(uint32_t, g01);
      pk.y = __builtin_bit_cast(uint32_t, g23);
      *(uint2*)&smem[hs(pi * 16 + lr, n0 + hi * 16 + lg * 4)] = pk;
    }
  }
  __syncthreads();

  // ---- GEMM2: D[px 64][out 64]; wave w does pixel rows 16w..16w+15 ----
  const int m0 = wv * 16;
  f32x4 acc2[4];
#pragma unroll
  for (int ni = 0; ni < 4; ++ni) acc2[ni] = 0;

  const half8v* w2v = (const half8v*)w2s;
  for (int ks = 0; ks < 8; ++ks) {
    half8v a2 = *(const half8v*)&smem[hs(m0 + lr, ks * 32 + lg * 8)];
#pragma unroll
    for (int ni = 0; ni < 4; ++ni) {
      half8v bfr = w2v[(ks * 4 + ni) * 64 + lane];
      acc2[ni] = __builtin_amdgcn_mfma_f32_16x16x32_f16(a2, bfr, acc2[ni],
                                                        0, 0, 0);
    }
  }

  // ---- epilogue: out = x + delta + b2 (x from fp16 copy; err <= 4e-3) ----
#pragma unroll
  for (int ni = 0; ni < 4; ++ni) {
    const int col  = ni * 16 + lr;
    const float bias = b2[col];
#pragma unroll
    for (int q = 0; q < 4; ++q) {
      const int row = m0 + lg * 4 + q;
      const int py = row >> 3, px = row & 7;
      const size_t idx =
          ((size_t)(batch * H_ + tileY + py) * W_ + (tileX + px)) * C_ + col;
      float xr = FP16X ? (float)xh[idx] : x[idx];
      out[idx] = xr + acc2[ni][q] + bias;
    }
  }
}

extern "C" void kernel_launch(void* const* d_in, const int* in_sizes, int n_in,
                              void* d_out, int out_size, void* d_ws,
                              size_t ws_size, hipStream_t stream) {
  const float* x  = (const float*)d_in[0];
  const float* cw = (const float*)d_in[1];
  const float* W1 = (const float*)d_in[2];
  const float* b1 = (const float*)d_in[3];
  const float* W2 = (const float*)d_in[4];
  const float* b2 = (const float*)d_in[5];
  float* out = (float*)d_out;

  _Float16* wsb = (_Float16*)d_ws;
  _Float16* w1s = wsb + W1S_OFF;
  _Float16* w2s = wsb + W2S_OFF;
  _Float16* cwh = wsb + CWH_OFF;
  _Float16* xh  = wsb + XH_OFF;

  cvt_weights_kernel<<<393, 256, 0, stream>>>(W1, W2, cw, w1s, w2s, cwh);

  const bool fp16x = ws_size >= (size_t)WS_NEED_BYTES;
  dim3 grid(W_ / 8, H_ / 8, B_);              // 4096 blocks
  if (fp16x) {
    cvt_x_kernel<<<XELEMS / 8 / 256, 256, 0, stream>>>(x, xh);
    nca_fused_kernel<true><<<grid, 256, 0, stream>>>(x, xh, cwh, b1, b2,
                                                     w1s, w2s, out);
  } else {
    nca_fused_kernel<false><<<grid, 256, 0, stream>>>(x, xh, cwh, b1, b2,
                                                      w1s, w2s, out);
  }
}